// Round 6
// baseline (82.420 us; speedup 1.0000x reference)
//
#include <hip/hip_runtime.h>
#include <math.h>

#define NB 8
#define NT 512
#define NM 8
#define ND 128
#define TC 8            // timesteps per block
#define WIN (TC + 15)   // z rows needed (halo 15)

// Integer Ramanujan sums c_q(n) = mu(q/g)*phi(q)/phi(q/g), g=gcd(n,q),
// q=1..16 (rows), n=0..15 (cols). Exact (the cos-sum is integer-valued).
__device__ __constant__ short RAMA_C[256] = {
    1,1,1,1,1,1,1,1,1,1,1,1,1,1,1,1,
    1,-1,1,-1,1,-1,1,-1,1,-1,1,-1,1,-1,1,-1,
    2,-1,-1,2,-1,-1,2,-1,-1,2,-1,-1,2,-1,-1,2,
    2,0,-2,0,2,0,-2,0,2,0,-2,0,2,0,-2,0,
    4,-1,-1,-1,-1,4,-1,-1,-1,-1,4,-1,-1,-1,-1,4,
    2,1,-1,-2,-1,1,2,1,-1,-2,-1,1,2,1,-1,-2,
    6,-1,-1,-1,-1,-1,-1,6,-1,-1,-1,-1,-1,-1,6,-1,
    4,0,0,0,-4,0,0,0,4,0,0,0,-4,0,0,0,
    6,0,0,-3,0,0,-3,0,0,6,0,0,-3,0,0,-3,
    4,1,-1,1,-1,-4,-1,1,-1,1,4,1,-1,1,-1,-4,
    10,-1,-1,-1,-1,-1,-1,-1,-1,-1,-1,10,-1,-1,-1,-1,
    4,0,2,0,-2,0,-4,0,-2,0,2,0,4,0,2,0,
    12,-1,-1,-1,-1,-1,-1,-1,-1,-1,-1,-1,-1,12,-1,-1,
    6,1,-1,1,-1,1,-1,-6,-1,1,-1,1,-1,1,6,1,
    8,1,1,-2,1,-4,-2,1,1,-2,-4,1,-2,1,1,8,
    8,0,0,0,0,0,0,0,-8,0,0,0,0,0,0,0
};

__global__ __launch_bounds__(512, 4) void rama_one_k(
    const float* __restrict__ z, const float* __restrict__ vm,
    const float* __restrict__ gw1, const float* __restrict__ gb1,
    const float* __restrict__ gw2, const float* __restrict__ gb2,
    const float* __restrict__ beta,
    float* __restrict__ out)
{
    __shared__ float Ks[256];
    __shared__ float za_s[WIN][9];                // padded: conflict-free gate reads
    __shared__ float vm_s[WIN][9];
    __shared__ __align__(16) float effs[8][TC][16];

    const int tid  = threadIdx.x;
    const int wv   = tid >> 6;       // wave 0..7 == channel m
    const int lane = tid & 63;
    const int blk  = blockIdx.x;
    const int tc   = blk & 63;       // 64 chunks of 8 t
    const int b    = blk >> 6;
    const int t0   = tc * TC;
    const int m    = wv;

    // --- normalized FIR bank from integer table (threads 0..255) ---
    if (tid < 256) {
        const int q = tid >> 4;
        float sum = 0.0f, ss = 0.0f;
        #pragma unroll
        for (int j = 0; j < 16; ++j) sum += (float)RAMA_C[q * 16 + j];
        const float mean = sum * (1.0f / 16.0f);
        #pragma unroll
        for (int j = 0; j < 16; ++j) {
            const float d = (float)RAMA_C[q * 16 + j] - mean;
            ss += d * d;
        }
        Ks[tid] = ((float)RAMA_C[tid] - mean) / sqrtf(fmaxf(ss, 1e-6f));
    }

    // --- phase 1: wave w loads its WIN-row z window ONCE; row-reduce -> za_s ---
    if (lane < WIN) {
        const int tt = t0 - 15 + lane;
        vm_s[lane][m] = (tt >= 0) ? vm[((size_t)b * NT + tt) * NM + m] : 0.0f;
    }
    float2 zr[WIN];
    #pragma unroll
    for (int j = 0; j < WIN; ++j) {
        const int tt = t0 - 15 + j;
        if (tt >= 0) {
            zr[j] = *(const float2*)(z + (((size_t)b * NT + tt) * NM + m) * ND + lane * 2);
        } else { zr[j].x = 0.0f; zr[j].y = 0.0f; }
    }
    #pragma unroll
    for (int j = 0; j < WIN; ++j) {
        float s = zr[j].x + zr[j].y;
        #pragma unroll
        for (int off = 32; off; off >>= 1) s += __shfl_xor(s, off, 64);
        if (lane == 0) za_s[j][m] = s * (1.0f / 128.0f) * vm_s[j][m];
    }
    __syncthreads();   // za_s, vm_s, Ks visible (only block-wide barrier)

    // --- phase 2: wave w's lanes<TC compute gates for its own m (t = t0+lane) ---
    if (lane < TC) {
        const int gi = lane;
        float rg[16];
        #pragma unroll
        for (int q = 0; q < 16; ++q) rg[q] = 0.0f;
        #pragma unroll
        for (int dly = 0; dly < 16; ++dly) {
            const int j  = gi + 15 - dly;
            const float k0 = Ks[(2 * m)     * 16 + 15 - dly];
            const float k1 = Ks[(2 * m + 1) * 16 + 15 - dly];
            #pragma unroll
            for (int m2 = 0; m2 < 8; ++m2) {
                const float zv = za_s[j][m2];
                rg[m2]     = fmaf(k0, zv, rg[m2]);     // q' = 0*8+m2
                rg[8 + m2] = fmaf(k1, zv, rg[8 + m2]); // q' = 1*8+m2
            }
        }
        float h1[16];
        #pragma unroll
        for (int q = 0; q < 16; ++q) {
            const float v = fmaf(rg[q], gw1[q], gb1[q]);
            h1[q] = 0.5f * v * (1.0f + erff(v * 0.70710678118654752440f));
        }
        float g[16];
        #pragma unroll
        for (int p = 0; p < 16; ++p) {
            float acc = gb2[p];
            #pragma unroll
            for (int q = 0; q < 16; ++q) acc = fmaf(h1[q], gw2[p * 16 + q], acc);
            g[p] = 1.0f / (1.0f + expf(-acc));
        }
        // fold beta*vm[t] (output) and vm[t-dly] (input mask) into taps
        const float sc = beta[0] * vm_s[gi + 15][m];
        float eff16[16];
        #pragma unroll
        for (int dly = 0; dly < 16; ++dly) {
            float acc = 0.0f;
            #pragma unroll
            for (int p = 0; p < 16; ++p) acc = fmaf(Ks[p * 16 + 15 - dly], g[p], acc);
            eff16[dly] = acc * vm_s[gi + 15 - dly][m] * sc;
        }
        float4* ep = (float4*)&effs[m][gi][0];
        ep[0] = make_float4(eff16[0],  eff16[1],  eff16[2],  eff16[3]);
        ep[1] = make_float4(eff16[4],  eff16[5],  eff16[6],  eff16[7]);
        ep[2] = make_float4(eff16[8],  eff16[9],  eff16[10], eff16[11]);
        ep[3] = make_float4(eff16[12], eff16[13], eff16[14], eff16[15]);
    }
    // effs[m] is produced and consumed by wave m only: same-wave LDS ordering,
    // no __syncthreads needed. Keep the scheduler from hoisting the reads:
    __builtin_amdgcn_wave_barrier();

    // --- phase 3: synthesis, wave w = m, TC t x 128 d from zr + broadcast effs ---
    #pragma unroll
    for (int i = 0; i < TC; ++i) {
        const float4 e0 = *(const float4*)&effs[m][i][0];
        const float4 e1 = *(const float4*)&effs[m][i][4];
        const float4 e2 = *(const float4*)&effs[m][i][8];
        const float4 e3 = *(const float4*)&effs[m][i][12];
        float px = 0.0f, py = 0.0f;
        #define ACC(EV, DLY) { const float2 zv = zr[15 + i - (DLY)]; \
                               px = fmaf((EV), zv.x, px); py = fmaf((EV), zv.y, py); }
        ACC(e0.x, 0)  ACC(e0.y, 1)  ACC(e0.z, 2)  ACC(e0.w, 3)
        ACC(e1.x, 4)  ACC(e1.y, 5)  ACC(e1.z, 6)  ACC(e1.w, 7)
        ACC(e2.x, 8)  ACC(e2.y, 9)  ACC(e2.z, 10) ACC(e2.w, 11)
        ACC(e3.x, 12) ACC(e3.y, 13) ACC(e3.z, 14) ACC(e3.w, 15)
        #undef ACC
        const float2 zraw = zr[15 + i];
        float2 hv;
        hv.x = zraw.x + px;            // beta & masks folded into effs
        hv.y = zraw.y + py;
        const int t = t0 + i;
        *(float2*)(out + (((size_t)b * NT + t) * NM + m) * ND + lane * 2) = hv;
    }
}

extern "C" void kernel_launch(void* const* d_in, const int* in_sizes, int n_in,
                              void* d_out, int out_size, void* d_ws, size_t ws_size,
                              hipStream_t stream) {
    const float* z    = (const float*)d_in[0];
    const float* vm   = (const float*)d_in[1];
    const float* gw1  = (const float*)d_in[2];
    const float* gb1  = (const float*)d_in[3];
    const float* gw2  = (const float*)d_in[4];
    const float* gb2  = (const float*)d_in[5];
    const float* beta = (const float*)d_in[6];
    float* out = (float*)d_out;

    rama_one_k<<<NB * (NT / TC), 512, 0, stream>>>(
        z, vm, gw1, gb1, gw2, gb2, beta, out);
}

// Round 7
// 41.287 us; speedup vs baseline: 1.9963x; 1.9963x over previous
//
#include <hip/hip_runtime.h>
#include <math.h>

#define NB 8
#define NT 512
#define NM 8
#define ND 128
#define TC 8            // timesteps per block
#define WIN (TC + 15)   // z rows needed (halo 15)

// Integer Ramanujan sums c_q(n) = mu(q/g)*phi(q)/phi(q/g), g=gcd(n,q),
// q=1..16 (rows), n=0..15 (cols). Exact (the cos-sum is integer-valued).
__device__ __constant__ short RAMA_C[256] = {
    1,1,1,1,1,1,1,1,1,1,1,1,1,1,1,1,
    1,-1,1,-1,1,-1,1,-1,1,-1,1,-1,1,-1,1,-1,
    2,-1,-1,2,-1,-1,2,-1,-1,2,-1,-1,2,-1,-1,2,
    2,0,-2,0,2,0,-2,0,2,0,-2,0,2,0,-2,0,
    4,-1,-1,-1,-1,4,-1,-1,-1,-1,4,-1,-1,-1,-1,4,
    2,1,-1,-2,-1,1,2,1,-1,-2,-1,1,2,1,-1,-2,
    6,-1,-1,-1,-1,-1,-1,6,-1,-1,-1,-1,-1,-1,6,-1,
    4,0,0,0,-4,0,0,0,4,0,0,0,-4,0,0,0,
    6,0,0,-3,0,0,-3,0,0,6,0,0,-3,0,0,-3,
    4,1,-1,1,-1,-4,-1,1,-1,1,4,1,-1,1,-1,-4,
    10,-1,-1,-1,-1,-1,-1,-1,-1,-1,-1,10,-1,-1,-1,-1,
    4,0,2,0,-2,0,-4,0,-2,0,2,0,4,0,2,0,
    12,-1,-1,-1,-1,-1,-1,-1,-1,-1,-1,-1,-1,12,-1,-1,
    6,1,-1,1,-1,1,-1,-6,-1,1,-1,1,-1,1,6,1,
    8,1,1,-2,1,-4,-2,1,1,-2,-4,1,-2,1,1,8,
    8,0,0,0,0,0,0,0,-8,0,0,0,0,0,0,0
};

// Plain __launch_bounds__(512): NO min-waves spec. R6's (512,4) forced
// VGPR=64 -> ~31MB scratch spill each way (FETCH 85MB / WRITE 47MB, 82us).
// Natural allocation ~100-128 VGPR -> 16 waves/CU -> 2 co-resident blocks.
__global__ __launch_bounds__(512) void rama_one_k(
    const float* __restrict__ z, const float* __restrict__ vm,
    const float* __restrict__ gw1, const float* __restrict__ gb1,
    const float* __restrict__ gw2, const float* __restrict__ gb2,
    const float* __restrict__ beta,
    float* __restrict__ out)
{
    __shared__ float Ks[256];
    __shared__ float za_s[WIN][9];                // padded: conflict-free gate reads
    __shared__ float vm_s[WIN][9];
    __shared__ __align__(16) float effs[8][TC][16];

    const int tid  = threadIdx.x;
    const int wv   = tid >> 6;       // wave 0..7 == channel m
    const int lane = tid & 63;
    const int blk  = blockIdx.x;
    const int tc   = blk & 63;       // 64 chunks of 8 t
    const int b    = blk >> 6;
    const int t0   = tc * TC;
    const int m    = wv;

    // --- normalized FIR bank from integer table (threads 0..255) ---
    if (tid < 256) {
        const int q = tid >> 4;
        float sum = 0.0f, ss = 0.0f;
        #pragma unroll
        for (int j = 0; j < 16; ++j) sum += (float)RAMA_C[q * 16 + j];
        const float mean = sum * (1.0f / 16.0f);
        #pragma unroll
        for (int j = 0; j < 16; ++j) {
            const float d = (float)RAMA_C[q * 16 + j] - mean;
            ss += d * d;
        }
        Ks[tid] = ((float)RAMA_C[tid] - mean) / sqrtf(fmaxf(ss, 1e-6f));
    }

    // --- phase 1: wave w loads its WIN-row z window ONCE; row-reduce -> za_s ---
    if (lane < WIN) {
        const int tt = t0 - 15 + lane;
        vm_s[lane][m] = (tt >= 0) ? vm[((size_t)b * NT + tt) * NM + m] : 0.0f;
    }
    float2 zr[WIN];
    #pragma unroll
    for (int j = 0; j < WIN; ++j) {
        const int tt = t0 - 15 + j;
        if (tt >= 0) {
            zr[j] = *(const float2*)(z + (((size_t)b * NT + tt) * NM + m) * ND + lane * 2);
        } else { zr[j].x = 0.0f; zr[j].y = 0.0f; }
    }
    #pragma unroll
    for (int j = 0; j < WIN; ++j) {
        float s = zr[j].x + zr[j].y;
        #pragma unroll
        for (int off = 32; off; off >>= 1) s += __shfl_xor(s, off, 64);
        if (lane == 0) za_s[j][m] = s * (1.0f / 128.0f) * vm_s[j][m];
    }
    __syncthreads();   // za_s, vm_s, Ks visible (only block-wide barrier)

    // --- phase 2: wave w's lanes<TC compute gates for its own m (t = t0+lane) ---
    if (lane < TC) {
        const int gi = lane;
        float rg[16];
        #pragma unroll
        for (int q = 0; q < 16; ++q) rg[q] = 0.0f;
        #pragma unroll
        for (int dly = 0; dly < 16; ++dly) {
            const int j  = gi + 15 - dly;
            const float k0 = Ks[(2 * m)     * 16 + 15 - dly];
            const float k1 = Ks[(2 * m + 1) * 16 + 15 - dly];
            #pragma unroll
            for (int m2 = 0; m2 < 8; ++m2) {
                const float zv = za_s[j][m2];
                rg[m2]     = fmaf(k0, zv, rg[m2]);     // q' = 0*8+m2
                rg[8 + m2] = fmaf(k1, zv, rg[8 + m2]); // q' = 1*8+m2
            }
        }
        // gelu in place: rg becomes h1
        #pragma unroll
        for (int q = 0; q < 16; ++q) {
            const float v = fmaf(rg[q], gw1[q], gb1[q]);
            rg[q] = 0.5f * v * (1.0f + erff(v * 0.70710678118654752440f));
        }
        float g[16];
        #pragma unroll
        for (int p = 0; p < 16; ++p) {
            float acc = gb2[p];
            #pragma unroll
            for (int q = 0; q < 16; ++q) acc = fmaf(rg[q], gw2[p * 16 + q], acc);
            g[p] = 1.0f / (1.0f + expf(-acc));
        }
        // fold beta*vm[t] (output) and vm[t-dly] (input mask) into taps
        const float sc = beta[0] * vm_s[gi + 15][m];
        float eff16[16];
        #pragma unroll
        for (int dly = 0; dly < 16; ++dly) {
            float acc = 0.0f;
            #pragma unroll
            for (int p = 0; p < 16; ++p) acc = fmaf(Ks[p * 16 + 15 - dly], g[p], acc);
            eff16[dly] = acc * vm_s[gi + 15 - dly][m] * sc;
        }
        float4* ep = (float4*)&effs[m][gi][0];
        ep[0] = make_float4(eff16[0],  eff16[1],  eff16[2],  eff16[3]);
        ep[1] = make_float4(eff16[4],  eff16[5],  eff16[6],  eff16[7]);
        ep[2] = make_float4(eff16[8],  eff16[9],  eff16[10], eff16[11]);
        ep[3] = make_float4(eff16[12], eff16[13], eff16[14], eff16[15]);
    }
    // effs[m] is produced and consumed by wave m only: same-wave LDS ordering,
    // no __syncthreads needed. Keep the scheduler from hoisting the reads:
    __builtin_amdgcn_wave_barrier();

    // --- phase 3: synthesis, wave w = m, TC t x 128 d from zr + broadcast effs ---
    #pragma unroll
    for (int i = 0; i < TC; ++i) {
        const float4 e0 = *(const float4*)&effs[m][i][0];
        const float4 e1 = *(const float4*)&effs[m][i][4];
        const float4 e2 = *(const float4*)&effs[m][i][8];
        const float4 e3 = *(const float4*)&effs[m][i][12];
        float px = 0.0f, py = 0.0f;
        #define ACC(EV, DLY) { const float2 zv = zr[15 + i - (DLY)]; \
                               px = fmaf((EV), zv.x, px); py = fmaf((EV), zv.y, py); }
        ACC(e0.x, 0)  ACC(e0.y, 1)  ACC(e0.z, 2)  ACC(e0.w, 3)
        ACC(e1.x, 4)  ACC(e1.y, 5)  ACC(e1.z, 6)  ACC(e1.w, 7)
        ACC(e2.x, 8)  ACC(e2.y, 9)  ACC(e2.z, 10) ACC(e2.w, 11)
        ACC(e3.x, 12) ACC(e3.y, 13) ACC(e3.z, 14) ACC(e3.w, 15)
        #undef ACC
        const float2 zraw = zr[15 + i];
        float2 hv;
        hv.x = zraw.x + px;            // beta & masks folded into effs
        hv.y = zraw.y + py;
        const int t = t0 + i;
        *(float2*)(out + (((size_t)b * NT + t) * NM + m) * ND + lane * 2) = hv;
    }
}

extern "C" void kernel_launch(void* const* d_in, const int* in_sizes, int n_in,
                              void* d_out, int out_size, void* d_ws, size_t ws_size,
                              hipStream_t stream) {
    const float* z    = (const float*)d_in[0];
    const float* vm   = (const float*)d_in[1];
    const float* gw1  = (const float*)d_in[2];
    const float* gb1  = (const float*)d_in[3];
    const float* gw2  = (const float*)d_in[4];
    const float* gb2  = (const float*)d_in[5];
    const float* beta = (const float*)d_in[6];
    float* out = (float*)d_out;

    rama_one_k<<<NB * (NT / TC), 512, 0, stream>>>(
        z, vm, gw1, gb1, gw2, gb2, beta, out);
}

// Round 8
// 31.078 us; speedup vs baseline: 2.6521x; 1.3285x over previous
//
#include <hip/hip_runtime.h>
#include <math.h>

#define NB 8
#define NT 512
#define NM 8
#define ND 128
#define TCB 32           // timesteps per block (K2)
#define TW  8            // timesteps per wave (K2)
#define WINW (TW + 15)   // 23: z rows per wave
#define WING (TCB + 15)  // 47: za rows per block

// Integer Ramanujan sums c_q(n) = mu(q/g)*phi(q)/phi(q/g), g=gcd(n,q),
// q=1..16 (rows), n=0..15 (cols). Exact (the cos-sum is integer-valued).
__device__ __constant__ short RAMA_C[256] = {
    1,1,1,1,1,1,1,1,1,1,1,1,1,1,1,1,
    1,-1,1,-1,1,-1,1,-1,1,-1,1,-1,1,-1,1,-1,
    2,-1,-1,2,-1,-1,2,-1,-1,2,-1,-1,2,-1,-1,2,
    2,0,-2,0,2,0,-2,0,2,0,-2,0,2,0,-2,0,
    4,-1,-1,-1,-1,4,-1,-1,-1,-1,4,-1,-1,-1,-1,4,
    2,1,-1,-2,-1,1,2,1,-1,-2,-1,1,2,1,-1,-2,
    6,-1,-1,-1,-1,-1,-1,6,-1,-1,-1,-1,-1,-1,6,-1,
    4,0,0,0,-4,0,0,0,4,0,0,0,-4,0,0,0,
    6,0,0,-3,0,0,-3,0,0,6,0,0,-3,0,0,-3,
    4,1,-1,1,-1,-4,-1,1,-1,1,4,1,-1,1,-1,-4,
    10,-1,-1,-1,-1,-1,-1,-1,-1,-1,-1,10,-1,-1,-1,-1,
    4,0,2,0,-2,0,-4,0,-2,0,2,0,4,0,2,0,
    12,-1,-1,-1,-1,-1,-1,-1,-1,-1,-1,-1,-1,12,-1,-1,
    6,1,-1,1,-1,1,-1,-6,-1,1,-1,1,-1,1,6,1,
    8,1,1,-2,1,-4,-2,1,1,-2,-4,1,-2,1,1,8,
    8,0,0,0,0,0,0,0,-8,0,0,0,0,0,0,0
};

// ---- K1: za[b][t][m] = mean_d z[b,t,m,d] * vm[b,t,m] ----
__global__ __launch_bounds__(256) void rama_reduce_k(
    const float* __restrict__ z, const float* __restrict__ vm,
    float* __restrict__ za)
{
    const int row = blockIdx.x * 8 + (threadIdx.x >> 5);   // (b*T+t)*M + m
    const int l   = threadIdx.x & 31;
    const float4 v = *(const float4*)(z + (size_t)row * ND + l * 4);
    float s = (v.x + v.y) + (v.z + v.w);
    #pragma unroll
    for (int off = 16; off; off >>= 1) s += __shfl_xor(s, off, 32);
    if (l == 0) za[row] = s * (1.0f / 128.0f) * vm[row];
}

// ---- K2: gate (wave0, 32 packed lanes) + synthesis (4 waves), barrier-cheap ----
__global__ __launch_bounds__(256) void rama_gs_k(
    const float* __restrict__ z, const float* __restrict__ vm,
    const float* __restrict__ gw1, const float* __restrict__ gb1,
    const float* __restrict__ gw2, const float* __restrict__ gb2,
    const float* __restrict__ beta,
    const float* __restrict__ za,
    float* __restrict__ out)
{
    __shared__ float Ks[256];
    __shared__ float za_s[WING][9];     // pad 9: stride-9 gate reads conflict-free
    __shared__ float vm_s[WING];
    __shared__ __align__(16) float effs[TCB][20];  // pad 20: rows 16B-aligned

    const int tid  = threadIdx.x;
    const int wv   = tid >> 6;
    const int lane = tid & 63;
    const int blk  = blockIdx.x;
    const int cks  = blk & 15;          // 16 chunks of 32 t
    const int m    = (blk >> 4) & 7;
    const int b    = blk >> 7;
    const int t0   = cks * TCB;
    const int tw   = t0 + wv * TW;

    // --- stage: Ks (256 thr), za window (376 consecutive floats), vm window ---
    {
        const int q = tid >> 4;
        float sum = 0.0f, ss = 0.0f;
        #pragma unroll
        for (int j = 0; j < 16; ++j) sum += (float)RAMA_C[q * 16 + j];
        const float mean = sum * (1.0f / 16.0f);
        #pragma unroll
        for (int j = 0; j < 16; ++j) {
            const float d = (float)RAMA_C[q * 16 + j] - mean;
            ss += d * d;
        }
        Ks[tid] = ((float)RAMA_C[tid] - mean) / sqrtf(fmaxf(ss, 1e-6f));
    }
    {
        const float* zab = za + (size_t)b * NT * NM;
        #pragma unroll
        for (int k = 0; k < 2; ++k) {
            const int i = tid + k * 256;
            if (i < WING * 8) {
                const int r  = i >> 3;
                const int tt = t0 - 15 + r;
                za_s[r][i & 7] = (tt >= 0) ? zab[tt * NM + (i & 7)] : 0.0f;
            }
        }
        if (tid < WING) {
            const int tt = t0 - 15 + tid;
            vm_s[tid] = (tt >= 0) ? vm[((size_t)b * NT + tt) * NM + m] : 0.0f;
        }
    }
    __syncthreads();   // cheap drain: only the small L2-hot staging loads

    // --- all waves: issue zr loads NOW (fly under the gate phase) ---
    float2 zr[WINW];
    #pragma unroll
    for (int j = 0; j < WINW; ++j) {
        const int tt = tw - 15 + j;     // wave-uniform condition
        if (tt >= 0) {
            zr[j] = *(const float2*)(z + (((size_t)b * NT + tt) * NM + m) * ND + lane * 2);
        } else { zr[j].x = 0.0f; zr[j].y = 0.0f; }
    }

    // --- wave0, lanes<32: all 32 gates, fully packed ---
    if (tid < 32) {
        const int gi = tid;             // t = t0 + gi
        float rg[16];
        #pragma unroll
        for (int q = 0; q < 16; ++q) rg[q] = 0.0f;
        #pragma unroll
        for (int dly = 0; dly < 16; ++dly) {
            const int j  = gi + 15 - dly;
            const float k0 = Ks[(2 * m)     * 16 + 15 - dly];   // block-uniform
            const float k1 = Ks[(2 * m + 1) * 16 + 15 - dly];
            #pragma unroll
            for (int m2 = 0; m2 < 8; ++m2) {
                const float zv = za_s[j][m2];
                rg[m2]     = fmaf(k0, zv, rg[m2]);     // q' = 0*8+m2
                rg[8 + m2] = fmaf(k1, zv, rg[8 + m2]); // q' = 1*8+m2
            }
        }
        #pragma unroll
        for (int q = 0; q < 16; ++q) {
            const float v = fmaf(rg[q], gw1[q], gb1[q]);
            rg[q] = 0.5f * v * (1.0f + erff(v * 0.70710678118654752440f));
        }
        float g[16];
        #pragma unroll
        for (int p = 0; p < 16; ++p) {
            float acc = gb2[p];
            #pragma unroll
            for (int q = 0; q < 16; ++q) acc = fmaf(rg[q], gw2[p * 16 + q], acc);
            g[p] = 1.0f / (1.0f + expf(-acc));
        }
        const float sc = beta[0] * vm_s[gi + 15];      // beta * vm[t]
        #pragma unroll
        for (int dly = 0; dly < 16; ++dly) {
            float acc = 0.0f;
            #pragma unroll
            for (int p = 0; p < 16; ++p) acc = fmaf(Ks[p * 16 + 15 - dly], g[p], acc);
            effs[gi][dly] = acc * vm_s[gi + 15 - dly] * sc;
        }
    }
    __syncthreads();   // drain: zr mostly landed during the gate phase

    // --- synthesis: wave w does 8 t x 128 d from zr + broadcast effs ---
    #pragma unroll
    for (int i = 0; i < TW; ++i) {
        const float* erow = &effs[wv * TW + i][0];
        const float4 e0 = *(const float4*)(erow + 0);
        const float4 e1 = *(const float4*)(erow + 4);
        const float4 e2 = *(const float4*)(erow + 8);
        const float4 e3 = *(const float4*)(erow + 12);
        float px = 0.0f, py = 0.0f;
        #define ACC(EV, DLY) { const float2 zv = zr[15 + i - (DLY)]; \
                               px = fmaf((EV), zv.x, px); py = fmaf((EV), zv.y, py); }
        ACC(e0.x, 0)  ACC(e0.y, 1)  ACC(e0.z, 2)  ACC(e0.w, 3)
        ACC(e1.x, 4)  ACC(e1.y, 5)  ACC(e1.z, 6)  ACC(e1.w, 7)
        ACC(e2.x, 8)  ACC(e2.y, 9)  ACC(e2.z, 10) ACC(e2.w, 11)
        ACC(e3.x, 12) ACC(e3.y, 13) ACC(e3.z, 14) ACC(e3.w, 15)
        #undef ACC
        const float2 zraw = zr[15 + i];
        float2 hv;
        hv.x = zraw.x + px;             // beta & masks folded into effs
        hv.y = zraw.y + py;
        const int t = tw + i;
        *(float2*)(out + (((size_t)b * NT + t) * NM + m) * ND + lane * 2) = hv;
    }
}

extern "C" void kernel_launch(void* const* d_in, const int* in_sizes, int n_in,
                              void* d_out, int out_size, void* d_ws, size_t ws_size,
                              hipStream_t stream) {
    const float* z    = (const float*)d_in[0];
    const float* vm   = (const float*)d_in[1];
    const float* gw1  = (const float*)d_in[2];
    const float* gb1  = (const float*)d_in[3];
    const float* gw2  = (const float*)d_in[4];
    const float* gb2  = (const float*)d_in[5];
    const float* beta = (const float*)d_in[6];
    float* out = (float*)d_out;

    float* za = (float*)d_ws;   // [B][T][M] = 32768 floats

    rama_reduce_k<<<(NB * NT * NM) / 8, 256, 0, stream>>>(z, vm, za);
    rama_gs_k<<<NB * NM * (NT / TCB), 256, 0, stream>>>(
        z, vm, gw1, gb1, gw2, gb2, beta, za, out);
}

// Round 9
// 28.506 us; speedup vs baseline: 2.8913x; 1.0902x over previous
//
#include <hip/hip_runtime.h>
#include <math.h>

#define NB 8
#define NT 512
#define NM 8
#define ND 128
#define TC 16   // timesteps per block

// Integer Ramanujan sums c_q(n) = mu(q/g)*phi(q)/phi(q/g), g=gcd(n,q),
// q=1..16 (rows), n=0..15 (cols). Exact (the cos-sum is integer-valued).
__device__ __constant__ short RAMA_C[256] = {
    1,1,1,1,1,1,1,1,1,1,1,1,1,1,1,1,
    1,-1,1,-1,1,-1,1,-1,1,-1,1,-1,1,-1,1,-1,
    2,-1,-1,2,-1,-1,2,-1,-1,2,-1,-1,2,-1,-1,2,
    2,0,-2,0,2,0,-2,0,2,0,-2,0,2,0,-2,0,
    4,-1,-1,-1,-1,4,-1,-1,-1,-1,4,-1,-1,-1,-1,4,
    2,1,-1,-2,-1,1,2,1,-1,-2,-1,1,2,1,-1,-2,
    6,-1,-1,-1,-1,-1,-1,6,-1,-1,-1,-1,-1,-1,6,-1,
    4,0,0,0,-4,0,0,0,4,0,0,0,-4,0,0,0,
    6,0,0,-3,0,0,-3,0,0,6,0,0,-3,0,0,-3,
    4,1,-1,1,-1,-4,-1,1,-1,1,4,1,-1,1,-1,-4,
    10,-1,-1,-1,-1,-1,-1,-1,-1,-1,-1,10,-1,-1,-1,-1,
    4,0,2,0,-2,0,-4,0,-2,0,2,0,4,0,2,0,
    12,-1,-1,-1,-1,-1,-1,-1,-1,-1,-1,-1,-1,12,-1,-1,
    6,1,-1,1,-1,1,-1,-6,-1,1,-1,1,-1,1,6,1,
    8,1,1,-2,1,-4,-2,1,1,-2,-4,1,-2,1,1,8,
    8,0,0,0,0,0,0,0,-8,0,0,0,0,0,0,0
};

// R5 structure (best measured: 28.25us = ~23us harness floor + 5.2us kernel,
// where 5.2us == the 33.6MB z-read+h-write HBM bound at 6.4TB/s).
// One kernel; z loaded ONCE into registers, serving both the D-mean
// reduction and the synthesis FIR; gates computed in LDS; no workspace.
__global__ __launch_bounds__(512, 1) void rama_one_k(
    const float* __restrict__ z, const float* __restrict__ vm,
    const float* __restrict__ gw1, const float* __restrict__ gb1,
    const float* __restrict__ gw2, const float* __restrict__ gb2,
    const float* __restrict__ beta,
    float* __restrict__ out)
{
    __shared__ float Ks[256];
    __shared__ float za_s[31][9];                 // padded: conflict-free gate reads
    __shared__ float vm_s[31][9];
    __shared__ __align__(16) float effs[8][16][16];

    const int tid  = threadIdx.x;
    const int wv   = tid >> 6;       // wave 0..7  == m for reduce/synthesis
    const int lane = tid & 63;
    const int blk  = blockIdx.x;
    const int tc   = blk & 31;       // 32 chunks of 16 t
    const int b    = blk >> 5;
    const int t0   = tc * TC;
    const int m    = wv;

    // --- normalized FIR bank from integer table (threads 0..255) ---
    if (tid < 256) {
        const int q = tid >> 4;
        float sum = 0.0f, ss = 0.0f;
        #pragma unroll
        for (int j = 0; j < 16; ++j) sum += (float)RAMA_C[q * 16 + j];
        const float mean = sum * (1.0f / 16.0f);
        #pragma unroll
        for (int j = 0; j < 16; ++j) {
            const float d = (float)RAMA_C[q * 16 + j] - mean;
            ss += d * d;
        }
        Ks[tid] = ((float)RAMA_C[tid] - mean) / sqrtf(fmaxf(ss, 1e-6f));
    }

    // --- phase 1: wave w loads its 31-row z window ONCE; reduce rows -> za_s ---
    if (lane < 31) {
        const int tt = t0 - 15 + lane;
        vm_s[lane][m] = (tt >= 0) ? vm[((size_t)b * NT + tt) * NM + m] : 0.0f;
    }
    float2 zr[31];
    #pragma unroll
    for (int j = 0; j < 31; ++j) {
        const int tt = t0 - 15 + j;
        if (tt >= 0) {
            zr[j] = *(const float2*)(z + (((size_t)b * NT + tt) * NM + m) * ND + lane * 2);
        } else { zr[j].x = 0.0f; zr[j].y = 0.0f; }
    }
    #pragma unroll
    for (int j = 0; j < 31; ++j) {
        float s = zr[j].x + zr[j].y;
        #pragma unroll
        for (int off = 32; off; off >>= 1) s += __shfl_xor(s, off, 64);
        if (lane == 0) za_s[j][m] = s * (1.0f / 128.0f) * vm_s[j][m];
    }
    __syncthreads();   // za_s, vm_s, Ks visible

    // --- phase 2: 128 gate threads (waves 0-1, fully packed) ---
    if (tid < 128) {
        const int gm = tid >> 4;     // filter/channel m
        const int gi = tid & 15;     // t = t0 + gi
        float rg[16];
        #pragma unroll
        for (int q = 0; q < 16; ++q) rg[q] = 0.0f;
        #pragma unroll
        for (int dly = 0; dly < 16; ++dly) {
            const int j  = gi + 15 - dly;
            const float k0 = Ks[(2 * gm)     * 16 + 15 - dly];
            const float k1 = Ks[(2 * gm + 1) * 16 + 15 - dly];
            #pragma unroll
            for (int m2 = 0; m2 < 8; ++m2) {
                const float zv = za_s[j][m2];
                rg[m2]     = fmaf(k0, zv, rg[m2]);     // q' = 0*8+m2
                rg[8 + m2] = fmaf(k1, zv, rg[8 + m2]); // q' = 1*8+m2
            }
        }
        float h1[16];
        #pragma unroll
        for (int q = 0; q < 16; ++q) {
            const float v = fmaf(rg[q], gw1[q], gb1[q]);
            h1[q] = 0.5f * v * (1.0f + erff(v * 0.70710678118654752440f));
        }
        float g[16];
        #pragma unroll
        for (int p = 0; p < 16; ++p) {
            float acc = gb2[p];
            #pragma unroll
            for (int q = 0; q < 16; ++q) acc = fmaf(h1[q], gw2[p * 16 + q], acc);
            g[p] = 1.0f / (1.0f + expf(-acc));
        }
        // fold beta*vm[t] (output) and vm[t-dly] (input mask) into taps
        const float sc = beta[0] * vm_s[gi + 15][gm];
        float eff16[16];
        #pragma unroll
        for (int dly = 0; dly < 16; ++dly) {
            float acc = 0.0f;
            #pragma unroll
            for (int p = 0; p < 16; ++p) acc = fmaf(Ks[p * 16 + 15 - dly], g[p], acc);
            eff16[dly] = acc * vm_s[gi + 15 - dly][gm] * sc;
        }
        float4* ep = (float4*)&effs[gm][gi][0];
        ep[0] = make_float4(eff16[0],  eff16[1],  eff16[2],  eff16[3]);
        ep[1] = make_float4(eff16[4],  eff16[5],  eff16[6],  eff16[7]);
        ep[2] = make_float4(eff16[8],  eff16[9],  eff16[10], eff16[11]);
        ep[3] = make_float4(eff16[12], eff16[13], eff16[14], eff16[15]);
    }
    __syncthreads();   // effs visible

    // --- phase 3: synthesis, wave w = m, 16 t x 128 d from zr + broadcast effs ---
    #pragma unroll
    for (int i = 0; i < TC; ++i) {
        const float4 e0 = *(const float4*)&effs[m][i][0];
        const float4 e1 = *(const float4*)&effs[m][i][4];
        const float4 e2 = *(const float4*)&effs[m][i][8];
        const float4 e3 = *(const float4*)&effs[m][i][12];
        float px = 0.0f, py = 0.0f;
        #define ACC(EV, DLY) { const float2 zv = zr[15 + i - (DLY)]; \
                               px = fmaf((EV), zv.x, px); py = fmaf((EV), zv.y, py); }
        ACC(e0.x, 0)  ACC(e0.y, 1)  ACC(e0.z, 2)  ACC(e0.w, 3)
        ACC(e1.x, 4)  ACC(e1.y, 5)  ACC(e1.z, 6)  ACC(e1.w, 7)
        ACC(e2.x, 8)  ACC(e2.y, 9)  ACC(e2.z, 10) ACC(e2.w, 11)
        ACC(e3.x, 12) ACC(e3.y, 13) ACC(e3.z, 14) ACC(e3.w, 15)
        #undef ACC
        const float2 zraw = zr[15 + i];
        float2 hv;
        hv.x = zraw.x + px;            // beta & masks folded into effs
        hv.y = zraw.y + py;
        const int t = t0 + i;
        *(float2*)(out + (((size_t)b * NT + t) * NM + m) * ND + lane * 2) = hv;
    }
}

extern "C" void kernel_launch(void* const* d_in, const int* in_sizes, int n_in,
                              void* d_out, int out_size, void* d_ws, size_t ws_size,
                              hipStream_t stream) {
    const float* z    = (const float*)d_in[0];
    const float* vm   = (const float*)d_in[1];
    const float* gw1  = (const float*)d_in[2];
    const float* gb1  = (const float*)d_in[3];
    const float* gw2  = (const float*)d_in[4];
    const float* gb2  = (const float*)d_in[5];
    const float* beta = (const float*)d_in[6];
    float* out = (float*)d_out;

    rama_one_k<<<NB * (NT / TC), 512, 0, stream>>>(
        z, vm, gw1, gb1, gw2, gb2, beta, out);
}